// Round 1
// baseline (335.684 us; speedup 1.0000x reference)
//
#include <hip/hip_runtime.h>
#include <math.h>

#define EMB 2048
#define NH 16
#define HD 128
#define BATCH 8
#define SEQ 16
#define KVLEN 4096
#define KSPLIT 4
#define MROWS (BATCH * SEQ) /* 128 */

__device__ __forceinline__ float dot4(float4 a, float4 b) {
  return a.x * b.x + a.y * b.y + a.z * b.z + a.w * b.w;
}

// ---------------------------------------------------------------------------
// GEMM: Y[r][d] = sum_c X[r][c] * W[d][c], optional fused RoPE (z<2) / bias.
// 256 threads. Block tile BM x BN, K-chunk 32. Thread: RR rows x CC cols.
// ---------------------------------------------------------------------------
template <int BM, int BN, int RR, int CC, bool ROPE, bool BIAS>
__global__ __launch_bounds__(256) void gemm_k(
    const float* __restrict__ X,
    const float* __restrict__ W0, const float* __restrict__ W1,
    const float* __restrict__ W2, const float* __restrict__ bias,
    float* __restrict__ Y0, float* __restrict__ Y1, float* __restrict__ Y2) {
  constexpr int BK = 32;
  static_assert((BM / RR) * (BN / CC) == 256, "thread mapping");
  const int z = blockIdx.z;
  const float* __restrict__ W = (z == 0) ? W0 : (z == 1) ? W1 : W2;
  float* __restrict__ Y = (z == 0) ? Y0 : (z == 1) ? Y1 : Y2;
  const int row0 = blockIdx.y * BM;
  const int col0 = blockIdx.x * BN;
  const int tid = threadIdx.x;

  __shared__ float xs[BK][BM + 4];
  __shared__ float wsm[BN][BK + 4];

  const int r0 = (tid % (BM / RR)) * RR;
  const int cl = (tid / (BM / RR)) * CC;

  float acc[RR][CC];
#pragma unroll
  for (int i = 0; i < RR; ++i)
#pragma unroll
    for (int jj = 0; jj < CC; ++jj) acc[i][jj] = 0.f;

  for (int k0 = 0; k0 < EMB; k0 += BK) {
    constexpr int XF4 = BM * (BK / 4);
#pragma unroll
    for (int i = 0; i < XF4 / 256; ++i) {
      int fi = tid + 256 * i;
      int r = fi >> 3, c4 = fi & 7;
      float4 v = *(const float4*)&X[(size_t)(row0 + r) * EMB + k0 + c4 * 4];
      xs[c4 * 4 + 0][r] = v.x;
      xs[c4 * 4 + 1][r] = v.y;
      xs[c4 * 4 + 2][r] = v.z;
      xs[c4 * 4 + 3][r] = v.w;
    }
    constexpr int WF4 = BN * (BK / 4);
#pragma unroll
    for (int i = 0; i < WF4 / 256; ++i) {
      int fi = tid + 256 * i;
      int d = fi >> 3, c4 = fi & 7;
      float4 v = *(const float4*)&W[(size_t)(col0 + d) * EMB + k0 + c4 * 4];
      *((float4*)&wsm[d][c4 * 4]) = v;
    }
    __syncthreads();
#pragma unroll
    for (int kk = 0; kk < BK; ++kk) {
      float a[RR];
#pragma unroll
      for (int i = 0; i < RR; ++i) a[i] = xs[kk][r0 + i];
      float wv[CC];
#pragma unroll
      for (int jj = 0; jj < CC; ++jj) wv[jj] = wsm[cl + jj][kk];
#pragma unroll
      for (int i = 0; i < RR; ++i)
#pragma unroll
        for (int jj = 0; jj < CC; ++jj)
          acc[i][jj] = fmaf(a[i], wv[jj], acc[i][jj]);
    }
    __syncthreads();
  }

  bool plain = true;
  if constexpr (ROPE) {
    static_assert(!ROPE || CC == 2, "rope needs even/odd pair per thread");
    if (z < 2) {
      plain = false;
#pragma unroll
      for (int i = 0; i < RR; ++i) {
        int gr = row0 + r0 + i;
        int gc = col0 + cl;  // even
        float pos = (float)(gr % SEQ);
        float invf = powf(10000.0f, -(float)(gc & (HD - 1)) * (1.0f / (float)HD));
        float ang = pos * invf;
        float sn, cs;
        sincosf(ang, &sn, &cs);
        float e = acc[i][0], o = acc[i][1];
        Y[(size_t)gr * EMB + gc] = e * cs - o * sn;
        Y[(size_t)gr * EMB + gc + 1] = e * sn + o * cs;
      }
    }
  }
  if (plain) {
#pragma unroll
    for (int i = 0; i < RR; ++i)
#pragma unroll
      for (int jj = 0; jj < CC; ++jj) {
        int gr = row0 + r0 + i, gc = col0 + cl + jj;
        float v = acc[i][jj];
        if constexpr (BIAS) v += bias[gc];
        Y[(size_t)gr * EMB + gc] = v;
      }
  }
}

// ---------------------------------------------------------------------------
// Flash-decoding attention partial. Grid (KSPLIT, NH, BATCH), 256 threads.
// Each block: one (b,h), one key-chunk. Partial m/l/O to workspace.
// Score phase: K in registers (thread = (key, d-group of 32)), Q broadcast
// from LDS, cross-dgroup reduce via LDS. PV phase: thread = (d, q-half).
// ---------------------------------------------------------------------------
__global__ __launch_bounds__(256) void attn_partial_k(
    const float* __restrict__ q, const float* __restrict__ knew,
    const float* __restrict__ vnew, const float* __restrict__ ck,
    const float* __restrict__ cv, const int* __restrict__ sp_ptr,
    float* __restrict__ po, float* __restrict__ pm, float* __restrict__ pl) {
  const int j = blockIdx.x, h = blockIdx.y, b = blockIdx.z;
  const int tid = threadIdx.x;
  const int sp = *sp_ptr;
  const int L = sp + SEQ;
  const int chunk = (L + KSPLIT - 1) / KSPLIT;
  const int c0 = j * chunk;
  const int c1 = min(L, c0 + chunk);

  __shared__ float Qs[SEQ][HD + 4];
  __shared__ float kv[64][HD + 4];
  __shared__ float part[4][SEQ][64];
  __shared__ float Pl[SEQ][64];
  __shared__ float scl[SEQ];

  const float qscale = 0.08838834764831845f;  // 1/sqrt(128)
#pragma unroll
  for (int i = 0; i < 2; ++i) {
    int fi = tid + 256 * i;
    int qr = fi >> 5, d4 = fi & 31;
    float4 v = *(const float4*)&q[(size_t)(b * SEQ + qr) * EMB + h * HD + d4 * 4];
    v.x *= qscale; v.y *= qscale; v.z *= qscale; v.w *= qscale;
    *((float4*)&Qs[qr][d4 * 4]) = v;
  }

  const int sk = tid & 63;        // score role: key in tile
  const int sg = tid >> 6;        // score role: d-group (32 floats)
  const int mq = tid >> 4;        // softmax role: q row
  const int mk = (tid & 15) * 4;  // softmax role: first key
  const int pd = tid & 127;       // PV role: d column
  const int pg = tid >> 7;        // PV role: q half

  float m = -1e30f, l = 0.f;
  float acc[8];
#pragma unroll
  for (int i = 0; i < 8; ++i) acc[i] = 0.f;

  __syncthreads();  // Qs ready

  for (int t0 = c0; t0 < c1; t0 += 64) {
    // --- K fragment to registers ---
    float4 kreg[8];
    {
      int gk = t0 + sk;
      const float* src = nullptr;
      if (gk < c1) {
        src = (gk < sp)
                  ? &ck[((size_t)b * KVLEN + gk) * EMB + h * HD + sg * 32]
                  : &knew[(size_t)(b * SEQ + gk - sp) * EMB + h * HD + sg * 32];
      }
#pragma unroll
      for (int i = 0; i < 8; ++i)
        kreg[i] = src ? ((const float4*)src)[i] : make_float4(0.f, 0.f, 0.f, 0.f);
    }
    // --- stage V tile into LDS ---
#pragma unroll
    for (int i = 0; i < 8; ++i) {
      int fi = tid + 256 * i;
      int key = fi >> 5, d4 = fi & 31;
      int gk = t0 + key;
      float4 v = make_float4(0.f, 0.f, 0.f, 0.f);
      if (gk < c1) {
        const float* src =
            (gk < sp) ? &cv[((size_t)b * KVLEN + gk) * EMB + h * HD]
                      : &vnew[(size_t)(b * SEQ + gk - sp) * EMB + h * HD];
        v = *(const float4*)&src[d4 * 4];
      }
      *((float4*)&kv[key][d4 * 4]) = v;
    }
    // --- partial scores: dot over this thread's 32-d slice ---
#pragma unroll
    for (int qq = 0; qq < SEQ; ++qq) {
      float s = 0.f;
#pragma unroll
      for (int i = 0; i < 8; ++i) {
        float4 qv = *(const float4*)&Qs[qq][sg * 32 + i * 4];
        s += dot4(kreg[i], qv);
      }
      part[sg][qq][sk] = s;
    }
    __syncthreads();
    // --- online softmax update (role: mq, keys mk..mk+3) ---
    float sv[4];
#pragma unroll
    for (int kk = 0; kk < 4; ++kk) {
      int k = mk + kk;
      sv[kk] = part[0][mq][k] + part[1][mq][k] + part[2][mq][k] + part[3][mq][k];
      if (t0 + k >= c1) sv[kk] = -3.0e38f;
    }
    float tmax = fmaxf(fmaxf(sv[0], sv[1]), fmaxf(sv[2], sv[3]));
#pragma unroll
    for (int off = 1; off < 16; off <<= 1)
      tmax = fmaxf(tmax, __shfl_xor(tmax, off, 16));
    float mnew = fmaxf(m, tmax);
    float scale = __expf(m - mnew);
    float ps = 0.f;
#pragma unroll
    for (int kk = 0; kk < 4; ++kk) {
      float p = __expf(sv[kk] - mnew);
      ps += p;
      Pl[mq][mk + kk] = p;
    }
#pragma unroll
    for (int off = 1; off < 16; off <<= 1) ps += __shfl_xor(ps, off, 16);
    l = l * scale + ps;
    m = mnew;
    if ((tid & 15) == 0) scl[mq] = scale;
    __syncthreads();
    // --- PV accumulate (role: pd column, pg q-half) ---
#pragma unroll
    for (int qi = 0; qi < 8; ++qi) acc[qi] *= scl[pg * 8 + qi];
#pragma unroll
    for (int kq = 0; kq < 16; ++kq) {
      float4 pq[8];
#pragma unroll
      for (int qi = 0; qi < 8; ++qi)
        pq[qi] = *(const float4*)&Pl[pg * 8 + qi][kq * 4];
#pragma unroll
      for (int kk = 0; kk < 4; ++kk) {
        float v = kv[kq * 4 + kk][pd];
        const float* pp0 = (const float*)&pq[0];
#pragma unroll
        for (int qi = 0; qi < 8; ++qi)
          acc[qi] = fmaf(((const float*)&pq[qi])[kk], v, acc[qi]);
        (void)pp0;
      }
    }
    __syncthreads();
  }

  const size_t pair = (size_t)(b * NH + h);
#pragma unroll
  for (int qi = 0; qi < 8; ++qi)
    po[((pair * KSPLIT + j) * SEQ + pg * 8 + qi) * HD + pd] = acc[qi];
  if ((tid & 15) == 0) {
    pm[(pair * KSPLIT + j) * SEQ + mq] = m;
    pl[(pair * KSPLIT + j) * SEQ + mq] = l;
  }
}

// ---------------------------------------------------------------------------
// Combine KSPLIT partials -> attention output (B,S,H*D) row-major.
// ---------------------------------------------------------------------------
__global__ __launch_bounds__(256) void combine_k(const float* __restrict__ po,
                                                 const float* __restrict__ pm,
                                                 const float* __restrict__ pl,
                                                 float* __restrict__ attn) {
  const int pair = blockIdx.x;
  const int b = pair / NH, h = pair % NH;
  const int tid = threadIdx.x;
  const int d = tid & 127, g = tid >> 7;
#pragma unroll
  for (int qi = 0; qi < 8; ++qi) {
    int qq = g * 8 + qi;
    float mj[KSPLIT], lj[KSPLIT];
    float Mx = -1e30f;
#pragma unroll
    for (int jj = 0; jj < KSPLIT; ++jj) {
      mj[jj] = pm[(pair * KSPLIT + jj) * SEQ + qq];
      lj[jj] = pl[(pair * KSPLIT + jj) * SEQ + qq];
      Mx = fmaxf(Mx, mj[jj]);
    }
    float Ls = 0.f, o = 0.f;
#pragma unroll
    for (int jj = 0; jj < KSPLIT; ++jj) {
      float w = __expf(mj[jj] - Mx);
      Ls += lj[jj] * w;
      o += po[((size_t)(pair * KSPLIT + jj) * SEQ + qq) * HD + d] * w;
    }
    attn[(size_t)(b * SEQ + qq) * EMB + h * HD + d] = o / Ls;
  }
}

// ---------------------------------------------------------------------------
extern "C" void kernel_launch(void* const* d_in, const int* in_sizes, int n_in,
                              void* d_out, int out_size, void* d_ws,
                              size_t ws_size, hipStream_t stream) {
  const float* x = (const float*)d_in[0];
  const float* Wq = (const float*)d_in[1];
  const float* Wk = (const float*)d_in[2];
  const float* Wv = (const float*)d_in[3];
  const float* Wo = (const float*)d_in[4];
  const float* bo = (const float*)d_in[5];
  const float* ck = (const float*)d_in[6];
  const float* cv = (const float*)d_in[7];
  const int* sp = (const int*)d_in[8];
  float* out = (float*)d_out;

  float* ws = (float*)d_ws;
  float* yq = ws;                  // 128*2048
  float* yk = ws + 262144;         // 128*2048
  float* yv = ws + 524288;         // 128*2048
  float* attn = ws + 786432;       // 128*2048
  float* po = ws + 1048576;        // 128*4*16*128 = 1048576
  float* pm = ws + 2097152;        // 8192
  float* pl = ws + 2105344;        // 8192

  // 1) QKV projections + fused RoPE on q,k
  gemm_k<64, 32, 4, 2, true, false>
      <<<dim3(EMB / 32, MROWS / 64, 3), 256, 0, stream>>>(
          x, Wq, Wk, Wv, nullptr, yq, yk, yv);

  // 2) flash-decoding attention partials
  attn_partial_k<<<dim3(KSPLIT, NH, BATCH), 256, 0, stream>>>(
      yq, yk, yv, ck, cv, sp, po, pm, pl);

  // 3) combine
  combine_k<<<dim3(BATCH * NH), 256, 0, stream>>>(po, pm, pl, attn);

  // 4) output projection + bias
  gemm_k<32, 32, 4, 1, false, true>
      <<<dim3(EMB / 32, MROWS / 32, 1), 256, 0, stream>>>(
          attn, Wo, Wo, Wo, bo, out, out, out);

  (void)in_sizes; (void)n_in; (void)out_size; (void)ws_size;
}